// Round 1
// baseline (650.417 us; speedup 1.0000x reference)
//
#include <hip/hip_runtime.h>
#include <hip/hip_bf16.h>
#include <math.h>

// Shapes: B=8, L=1024, D_MODEL=256, D_INNER=1024, D_STATE=32, D_CONV=8, DT_RANK=16
// BL = 8192 token rows. All GEMMs run bf16 MFMA (16x16x32), fp32 accumulate.
// Workspace use ~137 MB.

typedef float          f32x4 __attribute__((ext_vector_type(4)));
typedef short          s16x8 __attribute__((ext_vector_type(8)));
typedef unsigned short u16;
typedef u16            u16x4 __attribute__((ext_vector_type(4)));

#define DEV __device__ __forceinline__

DEV float bf2f(u16 u) { unsigned int i = ((unsigned int)u) << 16; return __builtin_bit_cast(float, i); }
DEV u16 f2bf(float f) {
  unsigned int x = __builtin_bit_cast(unsigned int, f);
  unsigned int r = (x + 0x7FFFu + ((x >> 16) & 1u)) >> 16;   // RNE
  return (u16)r;
}
DEV float sigmoidf_(float x) { return 1.0f / (1.0f + __expf(-x)); }

// ---------------- small cast kernels ----------------
__global__ void k_cast(const float* __restrict__ s, u16* __restrict__ d, int n) {
  int i = blockIdx.x * 256 + threadIdx.x;
  if (i < n) d[i] = f2bf(s[i]);
}
// dt_proj_w (1024,16) -> bf16 (1024,32) zero-padded in K
__global__ void k_pad_dtw(const float* __restrict__ s, u16* __restrict__ d) {
  int i = blockIdx.x * 256 + threadIdx.x;   // 1024*32
  int row = i >> 5, k = i & 31;
  d[i] = (k < 16) ? f2bf(s[row * 16 + k]) : (u16)0;
}
// dt = x_dbl[:, 0:16] -> bf16 [8192][16]
__global__ void k_cast_dt(const float* __restrict__ xdbl, u16* __restrict__ d) {
  int i = blockIdx.x * 256 + threadIdx.x;   // 8192*16
  int m = i >> 4, k = i & 15;
  d[i] = f2bf(xdbl[(size_t)m * 80 + k]);
}

// ---------------- LayerNorm: x fp32 (8192,256) -> xn bf16 ----------------
__global__ __launch_bounds__(256) void k_ln(const float* __restrict__ x,
    const float* __restrict__ w, const float* __restrict__ b, u16* __restrict__ xn) {
  int row  = blockIdx.x * 4 + (threadIdx.x >> 6);  // one wave per row
  int lane = threadIdx.x & 63;
  const float* xr = x + (size_t)row * 256 + lane * 4;
  f32x4 v = *(const f32x4*)xr;
  float s  = v[0] + v[1] + v[2] + v[3];
  float s2 = v[0]*v[0] + v[1]*v[1] + v[2]*v[2] + v[3]*v[3];
  for (int off = 32; off; off >>= 1) { s += __shfl_xor(s, off); s2 += __shfl_xor(s2, off); }
  float mu  = s * (1.0f / 256.0f);
  float inv = rsqrtf(s2 * (1.0f / 256.0f) - mu * mu + 1e-5f);
  int c = lane * 4;
  u16x4 o;
  #pragma unroll
  for (int t = 0; t < 4; ++t) o[t] = f2bf((v[t] - mu) * inv * w[c + t] + b[c + t]);
  *(u16x4*)(xn + (size_t)row * 256 + c) = o;
}

// ---------------- generic bf16 MFMA GEMM: C[M,N] = A[M,K] * W[N,K]^T ----------------
// EPI: 0 = fp32 out, 1 = bf16 out, 2 = softplus(acc + bias[col]) fp32, 3 = acc + resid fp32
template<int WAVES_M, int WAVES_N, int WM, int WN, int EPI>
__global__ __launch_bounds__(WAVES_M * WAVES_N * 64)
void k_gemm(const u16* __restrict__ A, const u16* __restrict__ Bw,
            float* __restrict__ Cf, u16* __restrict__ Cb,
            const float* __restrict__ extra,
            int lda, int ldb, int ldc, int Ktiles, int Kact) {
  constexpr int BM = WAVES_M * WM * 16;
  constexpr int BN = WAVES_N * WN * 16;
  constexpr int BK = 32, LDP = BK + 8;            // +8 shorts: 80B row stride, kills bank conflicts
  constexpr int THREADS = WAVES_M * WAVES_N * 64;
  __shared__ u16 As[BM][LDP];
  __shared__ u16 Bs[BN][LDP];
  const int tid = threadIdx.x;
  const int m0 = blockIdx.x * BM, n0 = blockIdx.y * BN;
  const int w = tid >> 6, lane = tid & 63;
  const int wm = w / WAVES_N, wn = w % WAVES_N;
  const int r = lane & 15, kg = lane >> 4, ks = kg * 8;

  f32x4 acc[WM][WN] = {};

  for (int kt = 0; kt < Ktiles; ++kt) {
    const int k0 = kt * BK;
    for (int ci = tid; ci < BM * 4; ci += THREADS) {       // stage A tile (guarded for Kact<K)
      int row = ci >> 2, k8 = (ci & 3) * 8;
      s16x8 vv = {0, 0, 0, 0, 0, 0, 0, 0};
      if (k0 + k8 < Kact)
        vv = *(const s16x8*)(A + (size_t)(m0 + row) * lda + k0 + k8);
      *(s16x8*)(&As[row][k8]) = vv;
    }
    for (int ci = tid; ci < BN * 4; ci += THREADS) {       // stage B tile
      int row = ci >> 2, k8 = (ci & 3) * 8;
      *(s16x8*)(&Bs[row][k8]) = *(const s16x8*)(Bw + (size_t)(n0 + row) * ldb + k0 + k8);
    }
    __syncthreads();
    s16x8 af[WM], bfr[WN];
    #pragma unroll
    for (int i = 0; i < WM; ++i) af[i]  = *(const s16x8*)(&As[wm * WM * 16 + i * 16 + r][ks]);
    #pragma unroll
    for (int j = 0; j < WN; ++j) bfr[j] = *(const s16x8*)(&Bs[wn * WN * 16 + j * 16 + r][ks]);
    #pragma unroll
    for (int i = 0; i < WM; ++i)
      #pragma unroll
      for (int j = 0; j < WN; ++j)
        acc[i][j] = __builtin_amdgcn_mfma_f32_16x16x32_bf16(af[i], bfr[j], acc[i][j], 0, 0, 0);
    __syncthreads();
  }

  #pragma unroll
  for (int i = 0; i < WM; ++i)
    #pragma unroll
    for (int j = 0; j < WN; ++j)
      #pragma unroll
      for (int q = 0; q < 4; ++q) {
        int gr = m0 + wm * WM * 16 + i * 16 + kg * 4 + q;  // C/D: row=(lane>>4)*4+reg
        int gc = n0 + wn * WN * 16 + j * 16 + r;           //       col=lane&15
        float v = acc[i][j][q];
        size_t idx = (size_t)gr * ldc + gc;
        if constexpr (EPI == 0) Cf[idx] = v;
        else if constexpr (EPI == 1) Cb[idx] = f2bf(v);
        else if constexpr (EPI == 2) {
          v += extra[gc];
          v = (v > 20.0f) ? v : log1pf(expf(v));           // softplus
          Cf[idx] = v;
        } else {
          Cf[idx] = v + extra[idx];                         // + residual
        }
      }
}

// ---------------- causal depthwise conv (K=8) + bias + SiLU ----------------
__global__ __launch_bounds__(256) void k_conv(const u16* __restrict__ xz,
    const float* __restrict__ cw, const float* __restrict__ cb, u16* __restrict__ u) {
  int d = (blockIdx.x & 3) * 256 + threadIdx.x;
  int m = blockIdx.x >> 2;
  int l = m & 1023;
  const f32x4* wv = (const f32x4*)(cw + (size_t)d * 8);
  f32x4 w0 = wv[0], w1 = wv[1];
  float acc = cb[d];
  #pragma unroll
  for (int j = 0; j < 8; ++j) {
    int li = l - 7 + j;
    float wj = (j < 4) ? w0[j] : w1[j - 4];
    if (li >= 0) acc = fmaf(bf2f(xz[(size_t)(m - 7 + j) * 2048 + d]), wj, acc);
  }
  u[(size_t)m * 1024 + d] = f2bf(acc * sigmoidf_(acc));
}

// ---------------- selective scan: thread per (d,n), DPP 32-lane reduce ----------------
template<int C, int RM, bool BC>
DEV float dpp_add(float x) {
  int s = __builtin_amdgcn_update_dpp(0, __builtin_bit_cast(int, x), C, RM, 0xf, BC);
  return x + __builtin_bit_cast(float, s);
}

__global__ __launch_bounds__(256) void k_scan(const float* __restrict__ delta,
    const u16* __restrict__ u, const float* __restrict__ xdbl,
    const float* __restrict__ A_log, float* __restrict__ y) {
  int b = blockIdx.x >> 7, dblk = blockIdx.x & 127;
  int n = threadIdx.x & 31, dloc = threadIdx.x >> 5;
  int d = dblk * 8 + dloc;
  float Adn = -__expf(A_log[d * 32 + n]);
  const float* dp = delta + (size_t)b * 1024 * 1024 + d;
  const u16*   up = u     + (size_t)b * 1024 * 1024 + d;
  const float* Bp = xdbl  + (size_t)b * 1024 * 80 + 16 + n;
  const float* Cp = xdbl  + (size_t)b * 1024 * 80 + 48 + n;
  float*       yp = y     + (size_t)b * 1024 * 1024 + d;
  float h = 0.0f;
  bool writer = ((threadIdx.x & 31) == 31);
  for (int l = 0; l < 1024; ++l) {
    float dv = dp[(size_t)l * 1024];
    float uv = bf2f(up[(size_t)l * 1024]);
    float Bn = Bp[(size_t)l * 80];
    float Cn = Cp[(size_t)l * 80];
    float dA = __expf(dv * Adn);
    h = fmaf(dA, h, dv * Bn * uv);
    float p = h * Cn;
    // sum over the 32 n-lanes: row_shr 1/2/4/8 then bcast15 into rows 1,3 -> lanes 31,63
    p = dpp_add<0x111, 0xf, true >(p);
    p = dpp_add<0x112, 0xf, true >(p);
    p = dpp_add<0x114, 0xf, true >(p);
    p = dpp_add<0x118, 0xf, true >(p);
    p = dpp_add<0x142, 0xa, false>(p);
    if (writer) yp[(size_t)l * 1024] = p;
  }
}

// ---------------- y_final = (y + u*D) * silu(z) -> bf16 ----------------
__global__ __launch_bounds__(256) void k_yfinal(const float* __restrict__ y,
    const u16* __restrict__ u, const u16* __restrict__ xz,
    const float* __restrict__ Dv, u16* __restrict__ yb) {
  int i = blockIdx.x * 256 + threadIdx.x;       // 8192*256 (4 elems each)
  int m = i >> 8, d = (i & 255) * 4;
  f32x4 yv = *(const f32x4*)(y + (size_t)m * 1024 + d);
  u16x4 uv = *(const u16x4*)(u + (size_t)m * 1024 + d);
  u16x4 zv = *(const u16x4*)(xz + (size_t)m * 2048 + 1024 + d);
  f32x4 Dw = *(const f32x4*)(Dv + d);
  u16x4 o;
  #pragma unroll
  for (int t = 0; t < 4; ++t) {
    float z = bf2f(zv[t]);
    float val = (yv[t] + bf2f(uv[t]) * Dw[t]) * (z * sigmoidf_(z));
    o[t] = f2bf(val);
  }
  *(u16x4*)(yb + (size_t)m * 1024 + d) = o;
}

extern "C" void kernel_launch(void* const* d_in, const int* in_sizes, int n_in,
                              void* d_out, int out_size, void* d_ws, size_t ws_size,
                              hipStream_t stream) {
  const float* x    = (const float*)d_in[0];
  const float* nw   = (const float*)d_in[1];
  const float* nb   = (const float*)d_in[2];
  const float* win  = (const float*)d_in[3];
  const float* cw   = (const float*)d_in[4];
  const float* cb   = (const float*)d_in[5];
  const float* wxp  = (const float*)d_in[6];
  const float* wdt  = (const float*)d_in[7];
  const float* dtb  = (const float*)d_in[8];
  const float* alog = (const float*)d_in[9];
  const float* Dv   = (const float*)d_in[10];
  const float* wout = (const float*)d_in[11];
  float* out = (float*)d_out;

  char* p = (char*)d_ws;
  auto alloc = [&](size_t bytes) { char* r = p; p += (bytes + 255) & ~(size_t)255; return r; };
  u16*   xn    = (u16*)  alloc((size_t)8192 * 256 * 2);
  u16*   winb  = (u16*)  alloc((size_t)2048 * 256 * 2);
  u16*   wxpb  = (u16*)  alloc((size_t)80 * 1024 * 2);
  u16*   wdtb  = (u16*)  alloc((size_t)1024 * 32 * 2);
  u16*   woutb = (u16*)  alloc((size_t)256 * 1024 * 2);
  u16*   xz    = (u16*)  alloc((size_t)8192 * 2048 * 2);  // [u | z] bf16
  u16*   ub    = (u16*)  alloc((size_t)8192 * 1024 * 2);  // silu(conv(u)) bf16
  float* xdbl  = (float*)alloc((size_t)8192 * 80 * 4);    // [dt | B | C] fp32
  u16*   dtbf  = (u16*)  alloc((size_t)8192 * 16 * 2);
  float* delta = (float*)alloc((size_t)8192 * 1024 * 4);
  float* ysc   = (float*)alloc((size_t)8192 * 1024 * 4);
  u16*   ybf   = (u16*)  alloc((size_t)8192 * 1024 * 2);

  // weight casts (every call: ws is re-poisoned)
  k_cast<<<2048, 256, 0, stream>>>(win, winb, 2048 * 256);
  k_cast<<<320, 256, 0, stream>>>(wxp, wxpb, 80 * 1024);
  k_pad_dtw<<<128, 256, 0, stream>>>(wdt, wdtb);
  k_cast<<<1024, 256, 0, stream>>>(wout, woutb, 256 * 1024);

  // 1. LayerNorm
  k_ln<<<2048, 256, 0, stream>>>(x, nw, nb, xn);
  // 2. in_proj: (8192,256)x(2048,256)^T -> xz bf16 (8192,2048)
  k_gemm<2, 2, 4, 4, 1><<<dim3(64, 16), 256, 0, stream>>>(xn, winb, nullptr, xz, nullptr,
                                                          256, 256, 2048, 8, 256);
  // 3. conv + SiLU -> u bf16 (8192,1024)
  k_conv<<<32768, 256, 0, stream>>>(xz, cw, cb, ub);
  // 4. x_proj: (8192,1024)x(80,1024)^T -> x_dbl fp32 (8192,80)
  k_gemm<2, 1, 1, 5, 0><<<dim3(256, 1), 128, 0, stream>>>(ub, wxpb, xdbl, nullptr, nullptr,
                                                          1024, 1024, 80, 32, 1024);
  // 5. dt cast + dt_proj (K=16 padded to 32) + softplus -> delta fp32 (8192,1024)
  k_cast_dt<<<512, 256, 0, stream>>>(xdbl, dtbf);
  k_gemm<2, 2, 4, 4, 2><<<dim3(64, 8), 256, 0, stream>>>(dtbf, wdtb, delta, nullptr, dtb,
                                                         16, 32, 1024, 1, 16);
  // 6. selective scan -> y fp32 (8192,1024)
  k_scan<<<1024, 256, 0, stream>>>(delta, ub, xdbl, alog, ysc);
  // 7. (y + u*D) * silu(z) -> bf16
  k_yfinal<<<8192, 256, 0, stream>>>(ysc, ub, xz, Dv, ybf);
  // 8. out_proj + residual -> d_out fp32 (8192,256)
  k_gemm<2, 2, 2, 2, 3><<<dim3(128, 4), 256, 0, stream>>>(ybf, woutb, out, nullptr, x,
                                                          1024, 1024, 256, 32, 1024);
}

// Round 2
// 439.757 us; speedup vs baseline: 1.4790x; 1.4790x over previous
//
#include <hip/hip_runtime.h>
#include <hip/hip_bf16.h>
#include <math.h>

// Shapes: B=8, L=1024, D_MODEL=256, D_INNER=1024, D_STATE=32, D_CONV=8, DT_RANK=16
// BL = 8192 token rows. All GEMMs run bf16 MFMA (16x16x32), fp32 accumulate.

typedef float          f32x4 __attribute__((ext_vector_type(4)));
typedef short          s16x8 __attribute__((ext_vector_type(8)));
typedef unsigned short u16;
typedef u16            u16x4 __attribute__((ext_vector_type(4)));

#define DEV __device__ __forceinline__

DEV float bf2f(u16 u) { unsigned int i = ((unsigned int)u) << 16; return __builtin_bit_cast(float, i); }
DEV u16 f2bf(float f) {
  unsigned int x = __builtin_bit_cast(unsigned int, f);
  unsigned int r = (x + 0x7FFFu + ((x >> 16) & 1u)) >> 16;   // RNE
  return (u16)r;
}
DEV float sigmoidf_(float x) { return 1.0f / (1.0f + __expf(-x)); }

// ---------------- small cast kernels ----------------
__global__ void k_cast(const float* __restrict__ s, u16* __restrict__ d, int n) {
  int i = blockIdx.x * 256 + threadIdx.x;
  if (i < n) d[i] = f2bf(s[i]);
}
// dt_proj_w (1024,16) -> bf16 (1024,32) zero-padded in K
__global__ void k_pad_dtw(const float* __restrict__ s, u16* __restrict__ d) {
  int i = blockIdx.x * 256 + threadIdx.x;   // 1024*32
  int row = i >> 5, k = i & 31;
  d[i] = (k < 16) ? f2bf(s[row * 16 + k]) : (u16)0;
}
// dt = x_dbl[:, 0:16] -> bf16 [8192][16]
__global__ void k_cast_dt(const float* __restrict__ xdbl, u16* __restrict__ d) {
  int i = blockIdx.x * 256 + threadIdx.x;   // 8192*16
  int m = i >> 4, k = i & 15;
  d[i] = f2bf(xdbl[(size_t)m * 80 + k]);
}

// ---------------- LayerNorm: x fp32 (8192,256) -> xn bf16 ----------------
__global__ __launch_bounds__(256) void k_ln(const float* __restrict__ x,
    const float* __restrict__ w, const float* __restrict__ b, u16* __restrict__ xn) {
  int row  = blockIdx.x * 4 + (threadIdx.x >> 6);  // one wave per row
  int lane = threadIdx.x & 63;
  const float* xr = x + (size_t)row * 256 + lane * 4;
  f32x4 v = *(const f32x4*)xr;
  float s  = v[0] + v[1] + v[2] + v[3];
  float s2 = v[0]*v[0] + v[1]*v[1] + v[2]*v[2] + v[3]*v[3];
  for (int off = 32; off; off >>= 1) { s += __shfl_xor(s, off); s2 += __shfl_xor(s2, off); }
  float mu  = s * (1.0f / 256.0f);
  float inv = rsqrtf(s2 * (1.0f / 256.0f) - mu * mu + 1e-5f);
  int c = lane * 4;
  u16x4 o;
  #pragma unroll
  for (int t = 0; t < 4; ++t) o[t] = f2bf((v[t] - mu) * inv * w[c + t] + b[c + t]);
  *(u16x4*)(xn + (size_t)row * 256 + c) = o;
}

// ---------------- generic bf16 MFMA GEMM: C[M,N] = A[M,K] * W[N,K]^T ----------------
// EPI: 0 = fp32 out, 1 = bf16 out, 2 = softplus(acc + bias[col]) fp32, 3 = acc + resid fp32
template<int WAVES_M, int WAVES_N, int WM, int WN, int EPI>
__global__ __launch_bounds__(WAVES_M * WAVES_N * 64)
void k_gemm(const u16* __restrict__ A, const u16* __restrict__ Bw,
            float* __restrict__ Cf, u16* __restrict__ Cb,
            const float* __restrict__ extra,
            int lda, int ldb, int ldc, int Ktiles, int Kact) {
  constexpr int BM = WAVES_M * WM * 16;
  constexpr int BN = WAVES_N * WN * 16;
  constexpr int BK = 32, LDP = BK + 8;            // +8 shorts: 80B row stride, kills bank conflicts
  constexpr int THREADS = WAVES_M * WAVES_N * 64;
  __shared__ u16 As[BM][LDP];
  __shared__ u16 Bs[BN][LDP];
  const int tid = threadIdx.x;
  const int m0 = blockIdx.x * BM, n0 = blockIdx.y * BN;
  const int w = tid >> 6, lane = tid & 63;
  const int wm = w / WAVES_N, wn = w % WAVES_N;
  const int r = lane & 15, kg = lane >> 4, ks = kg * 8;

  f32x4 acc[WM][WN] = {};

  for (int kt = 0; kt < Ktiles; ++kt) {
    const int k0 = kt * BK;
    for (int ci = tid; ci < BM * 4; ci += THREADS) {       // stage A tile (guarded for Kact<K)
      int row = ci >> 2, k8 = (ci & 3) * 8;
      s16x8 vv = {0, 0, 0, 0, 0, 0, 0, 0};
      if (k0 + k8 < Kact)
        vv = *(const s16x8*)(A + (size_t)(m0 + row) * lda + k0 + k8);
      *(s16x8*)(&As[row][k8]) = vv;
    }
    for (int ci = tid; ci < BN * 4; ci += THREADS) {       // stage B tile
      int row = ci >> 2, k8 = (ci & 3) * 8;
      *(s16x8*)(&Bs[row][k8]) = *(const s16x8*)(Bw + (size_t)(n0 + row) * ldb + k0 + k8);
    }
    __syncthreads();
    s16x8 af[WM], bfr[WN];
    #pragma unroll
    for (int i = 0; i < WM; ++i) af[i]  = *(const s16x8*)(&As[wm * WM * 16 + i * 16 + r][ks]);
    #pragma unroll
    for (int j = 0; j < WN; ++j) bfr[j] = *(const s16x8*)(&Bs[wn * WN * 16 + j * 16 + r][ks]);
    #pragma unroll
    for (int i = 0; i < WM; ++i)
      #pragma unroll
      for (int j = 0; j < WN; ++j)
        acc[i][j] = __builtin_amdgcn_mfma_f32_16x16x32_bf16(af[i], bfr[j], acc[i][j], 0, 0, 0);
    __syncthreads();
  }

  #pragma unroll
  for (int i = 0; i < WM; ++i)
    #pragma unroll
    for (int j = 0; j < WN; ++j)
      #pragma unroll
      for (int q = 0; q < 4; ++q) {
        int gr = m0 + wm * WM * 16 + i * 16 + kg * 4 + q;  // C/D: row=(lane>>4)*4+reg
        int gc = n0 + wn * WN * 16 + j * 16 + r;           //       col=lane&15
        float v = acc[i][j][q];
        size_t idx = (size_t)gr * ldc + gc;
        if constexpr (EPI == 0) Cf[idx] = v;
        else if constexpr (EPI == 1) Cb[idx] = f2bf(v);
        else if constexpr (EPI == 2) {
          v += extra[gc];
          v = (v > 20.0f) ? v : log1pf(expf(v));           // softplus
          Cf[idx] = v;
        } else {
          Cf[idx] = v + extra[idx];                         // + residual
        }
      }
}

// ---------------- causal depthwise conv (K=8) + bias + SiLU ----------------
__global__ __launch_bounds__(256) void k_conv(const u16* __restrict__ xz,
    const float* __restrict__ cw, const float* __restrict__ cb, u16* __restrict__ u) {
  int d = (blockIdx.x & 3) * 256 + threadIdx.x;
  int m = blockIdx.x >> 2;
  int l = m & 1023;
  const f32x4* wv = (const f32x4*)(cw + (size_t)d * 8);
  f32x4 w0 = wv[0], w1 = wv[1];
  float acc = cb[d];
  #pragma unroll
  for (int j = 0; j < 8; ++j) {
    int li = l - 7 + j;
    float wj = (j < 4) ? w0[j] : w1[j - 4];
    if (li >= 0) acc = fmaf(bf2f(xz[(size_t)(m - 7 + j) * 2048 + d]), wj, acc);
  }
  u[(size_t)m * 1024 + d] = f2bf(acc * sigmoidf_(acc));
}

// ---------------- selective scan ----------------
// Thread per (d,n); l chunked by 64, B/C/delta/u staged via double-buffered LDS.
// T14 async-stage: issue next chunk's global loads before this chunk's compute;
// ds_write + single barrier after. DPP 32-lane reduce for y = sum_n h*C.
template<int C, int RM, bool BC>
DEV float dpp_add(float x) {
  int s = __builtin_amdgcn_update_dpp(0, __builtin_bit_cast(int, x), C, RM, 0xf, BC);
  return x + __builtin_bit_cast(float, s);
}

__global__ __launch_bounds__(256) void k_scan(const float* __restrict__ delta,
    const u16* __restrict__ u, const float* __restrict__ xdbl,
    const float* __restrict__ A_log, float* __restrict__ y) {
  constexpr int CH = 64, NC = 1024 / CH;
  __shared__ float sB[2][CH][32];   // 16 KB
  __shared__ float sC[2][CH][32];   // 16 KB
  __shared__ float sD[2][CH][8];    //  4 KB
  __shared__ float sU[2][CH][8];    //  4 KB  (total 40 KB -> 4 blocks/CU)
  const int b = blockIdx.x >> 7, dblk = blockIdx.x & 127;
  const int d0 = dblk * 8;
  const int t = threadIdx.x;
  const int n = t & 31, dloc = t >> 5;
  const int d = d0 + dloc;
  // fold log2(e) into A so the inner exp is a raw exp2
  const float Adn = -__expf(A_log[d * 32 + n]) * 1.442695040888963f;
  const size_t mrow0 = (size_t)b * 1024;
  // staging thread->element mapping
  const int bcRow = t >> 5, bcCol = t & 31;   // B/C: 8 rows x 32 cols per pass, 8 passes
  const int dRow  = t >> 3, dCol  = t & 7;    // delta: 32 rows x 8 cols per pass, 2 passes
  const int uRow  = t >> 2, uCol  = (t & 3) * 2; // u: 64 rows x 4 lane-pairs, 1 pass

  float rB[8], rC[8], rD[2], rU[2];

  auto load_chunk = [&](int c) {
    const int l0 = c * CH;
    #pragma unroll
    for (int i = 0; i < 8; ++i) {
      size_t m = mrow0 + l0 + bcRow + 8 * i;
      rB[i] = xdbl[m * 80 + 16 + bcCol];
      rC[i] = xdbl[m * 80 + 48 + bcCol];
    }
    #pragma unroll
    for (int i = 0; i < 2; ++i)
      rD[i] = delta[(mrow0 + l0 + dRow + 32 * i) * 1024 + d0 + dCol];
    const u16* up = u + (mrow0 + l0 + uRow) * 1024 + d0 + uCol;
    rU[0] = bf2f(up[0]); rU[1] = bf2f(up[1]);
  };
  auto write_chunk = [&](int buf) {
    #pragma unroll
    for (int i = 0; i < 8; ++i) {
      sB[buf][bcRow + 8 * i][bcCol] = rB[i];
      sC[buf][bcRow + 8 * i][bcCol] = rC[i];
    }
    #pragma unroll
    for (int i = 0; i < 2; ++i) sD[buf][dRow + 32 * i][dCol] = rD[i];
    sU[buf][uRow][uCol] = rU[0]; sU[buf][uRow][uCol + 1] = rU[1];
  };

  load_chunk(0);
  write_chunk(0);
  __syncthreads();

  float h = 0.0f;
  float* yp = y + mrow0 * 1024 + d;
  const bool writer = ((t & 31) == 31);
  for (int c = 0; c < NC; ++c) {
    const int cur = c & 1;
    if (c + 1 < NC) load_chunk(c + 1);         // in flight during compute (T14)
    const int l0 = c * CH;
    #pragma unroll 4
    for (int l = 0; l < CH; ++l) {
      float dv = sD[cur][l][dloc];             // broadcast (free)
      float uv = sU[cur][l][dloc];             // broadcast (free)
      float Bn = sB[cur][l][n];                // banks 0..31, conflict-free
      float Cn = sC[cur][l][n];
      float dA = exp2f(dv * Adn);
      h = fmaf(dA, h, dv * Bn * uv);
      float p = h * Cn;
      p = dpp_add<0x111, 0xf, true >(p);       // row_shr 1/2/4/8 + bcast15
      p = dpp_add<0x112, 0xf, true >(p);
      p = dpp_add<0x114, 0xf, true >(p);
      p = dpp_add<0x118, 0xf, true >(p);
      p = dpp_add<0x142, 0xa, false>(p);
      if (writer) yp[(size_t)(l0 + l) * 1024] = p;
    }
    if (c + 1 < NC) {
      write_chunk(cur ^ 1);                    // prev readers of buf^1 already barriered
      __syncthreads();
    }
  }
}

// ---------------- y_final = (y + u*D) * silu(z) -> bf16 ----------------
__global__ __launch_bounds__(256) void k_yfinal(const float* __restrict__ y,
    const u16* __restrict__ u, const u16* __restrict__ xz,
    const float* __restrict__ Dv, u16* __restrict__ yb) {
  int i = blockIdx.x * 256 + threadIdx.x;       // 8192*256 (4 elems each)
  int m = i >> 8, d = (i & 255) * 4;
  f32x4 yv = *(const f32x4*)(y + (size_t)m * 1024 + d);
  u16x4 uv = *(const u16x4*)(u + (size_t)m * 1024 + d);
  u16x4 zv = *(const u16x4*)(xz + (size_t)m * 2048 + 1024 + d);
  f32x4 Dw = *(const f32x4*)(Dv + d);
  u16x4 o;
  #pragma unroll
  for (int t = 0; t < 4; ++t) {
    float z = bf2f(zv[t]);
    float val = (yv[t] + bf2f(uv[t]) * Dw[t]) * (z * sigmoidf_(z));
    o[t] = f2bf(val);
  }
  *(u16x4*)(yb + (size_t)m * 1024 + d) = o;
}

extern "C" void kernel_launch(void* const* d_in, const int* in_sizes, int n_in,
                              void* d_out, int out_size, void* d_ws, size_t ws_size,
                              hipStream_t stream) {
  const float* x    = (const float*)d_in[0];
  const float* nw   = (const float*)d_in[1];
  const float* nb   = (const float*)d_in[2];
  const float* win  = (const float*)d_in[3];
  const float* cw   = (const float*)d_in[4];
  const float* cb   = (const float*)d_in[5];
  const float* wxp  = (const float*)d_in[6];
  const float* wdt  = (const float*)d_in[7];
  const float* dtb  = (const float*)d_in[8];
  const float* alog = (const float*)d_in[9];
  const float* Dv   = (const float*)d_in[10];
  const float* wout = (const float*)d_in[11];
  float* out = (float*)d_out;

  char* p = (char*)d_ws;
  auto alloc = [&](size_t bytes) { char* r = p; p += (bytes + 255) & ~(size_t)255; return r; };
  u16*   xn    = (u16*)  alloc((size_t)8192 * 256 * 2);
  u16*   winb  = (u16*)  alloc((size_t)2048 * 256 * 2);
  u16*   wxpb  = (u16*)  alloc((size_t)80 * 1024 * 2);
  u16*   wdtb  = (u16*)  alloc((size_t)1024 * 32 * 2);
  u16*   woutb = (u16*)  alloc((size_t)256 * 1024 * 2);
  u16*   xz    = (u16*)  alloc((size_t)8192 * 2048 * 2);  // [u | z] bf16
  u16*   ub    = (u16*)  alloc((size_t)8192 * 1024 * 2);  // silu(conv(u)) bf16
  float* xdbl  = (float*)alloc((size_t)8192 * 80 * 4);    // [dt | B | C] fp32
  u16*   dtbf  = (u16*)  alloc((size_t)8192 * 16 * 2);
  float* delta = (float*)alloc((size_t)8192 * 1024 * 4);
  float* ysc   = (float*)alloc((size_t)8192 * 1024 * 4);
  u16*   ybf   = (u16*)  alloc((size_t)8192 * 1024 * 2);

  // weight casts (every call: ws is re-poisoned)
  k_cast<<<2048, 256, 0, stream>>>(win, winb, 2048 * 256);
  k_cast<<<320, 256, 0, stream>>>(wxp, wxpb, 80 * 1024);
  k_pad_dtw<<<128, 256, 0, stream>>>(wdt, wdtb);
  k_cast<<<1024, 256, 0, stream>>>(wout, woutb, 256 * 1024);

  // 1. LayerNorm
  k_ln<<<2048, 256, 0, stream>>>(x, nw, nb, xn);
  // 2. in_proj: (8192,256)x(2048,256)^T -> xz bf16 (8192,2048)
  k_gemm<2, 2, 4, 4, 1><<<dim3(64, 16), 256, 0, stream>>>(xn, winb, nullptr, xz, nullptr,
                                                          256, 256, 2048, 8, 256);
  // 3. conv + SiLU -> u bf16 (8192,1024)
  k_conv<<<32768, 256, 0, stream>>>(xz, cw, cb, ub);
  // 4. x_proj: (8192,1024)x(80,1024)^T -> x_dbl fp32 (8192,80)
  k_gemm<2, 1, 1, 5, 0><<<dim3(256, 1), 128, 0, stream>>>(ub, wxpb, xdbl, nullptr, nullptr,
                                                          1024, 1024, 80, 32, 1024);
  // 5. dt cast + dt_proj (K=16 padded to 32) + softplus -> delta fp32 (8192,1024)
  k_cast_dt<<<512, 256, 0, stream>>>(xdbl, dtbf);
  k_gemm<2, 2, 4, 4, 2><<<dim3(64, 8), 256, 0, stream>>>(dtbf, wdtb, delta, nullptr, dtb,
                                                         16, 32, 1024, 1, 16);
  // 6. selective scan -> y fp32 (8192,1024)
  k_scan<<<1024, 256, 0, stream>>>(delta, ub, xdbl, alog, ysc);
  // 7. (y + u*D) * silu(z) -> bf16
  k_yfinal<<<8192, 256, 0, stream>>>(ysc, ub, xz, Dv, ybf);
  // 8. out_proj + residual -> d_out fp32 (8192,256)
  k_gemm<2, 2, 2, 2, 3><<<dim3(128, 4), 256, 0, stream>>>(ybf, woutb, out, nullptr, x,
                                                          1024, 1024, 256, 32, 1024);
}